// Round 1
// baseline (972.131 us; speedup 1.0000x reference)
//
#include <hip/hip_runtime.h>

// ---------------------------------------------------------------------------
// TiedMultiheadAttention  (B=1, N=64, L=512, D=768, H=12, DK=64)
//
// Pipeline (all GEMMs bf16-MFMA 16x16x32, fp32 accumulate):
//   s1: Q = (query @ Wq^T + bq) * 1/64   -> q_ws  [h][i][n*64+k]   bf16
//       K =  key   @ Wk^T + bk           -> k_ws  [h][j][n*64+k]   bf16
//       V =  value @ Wv^T + bv           -> vt_ws [h][n*64+k][j]   bf16 (transposed)
//   s2: att[h][i][j] = Qcat_h @ Kcat_h^T  (K-dim 4096)             fp32
//   s3: softmax rows -> att_b bf16
//   s4: out_h = att_b_h @ Vt_h^T  -> out_ws [(n*512+i)][h*64+k]    bf16
//   s5: Y = out_ws @ Wo^T + bo -> d_out                            fp32
// ---------------------------------------------------------------------------

typedef __bf16 bf16x8 __attribute__((ext_vector_type(8)));
typedef float f32x4 __attribute__((ext_vector_type(4)));

__device__ __forceinline__ unsigned short f2bf(float f) {
  unsigned u = __float_as_uint(f);
  u += 0x7fffu + ((u >> 16) & 1u);   // round-to-nearest-even
  return (unsigned short)(u >> 16);
}

// stage 8 elements (one row-chunk) into LDS as bf16
__device__ __forceinline__ void stage8(unsigned short* dst, const float* __restrict__ src) {
  const float4* s = (const float4*)src;
  float4 x = s[0];
  float4 y = s[1];
  uint4 p;
  p.x = (unsigned)f2bf(x.x) | ((unsigned)f2bf(x.y) << 16);
  p.y = (unsigned)f2bf(x.z) | ((unsigned)f2bf(x.w) << 16);
  p.z = (unsigned)f2bf(y.x) | ((unsigned)f2bf(y.y) << 16);
  p.w = (unsigned)f2bf(y.z) | ((unsigned)f2bf(y.w) << 16);
  *(uint4*)dst = p;
}
__device__ __forceinline__ void stage8(unsigned short* dst, const unsigned short* __restrict__ src) {
  *(uint4*)dst = *(const uint4*)src;
}

enum { MODE_QCAT = 0, MODE_VT = 1, MODE_ATT = 2, MODE_OUTWS = 3, MODE_OUT_BIAS = 4 };

constexpr int BM = 64, BN = 64, BK = 32;
constexpr int LDSP = 40;  // padded row stride (bf16 elems): 80B -> only 2-way bank alias (free)

// C = A @ B^T;  A:[M,K] lda, B:[N,K] ldb (row-major), optional batch strides.
template <typename TA, typename TB, int MODE>
__global__ __launch_bounds__(256) void gemm_bt(
    const TA* __restrict__ A, const TB* __restrict__ B,
    const float* __restrict__ bias, void* __restrict__ Cv,
    int M, int N, int K, int lda, int ldb,
    long long a_bstride, long long b_bstride, float alpha) {
  __shared__ unsigned short As[BM][LDSP];
  __shared__ unsigned short Bs[BN][LDSP];

  const int tid = threadIdx.x;
  const int wave = tid >> 6;
  const int lane = tid & 63;
  const int batch = blockIdx.z;
  const long long m0 = (long long)blockIdx.y * BM;
  const long long n0 = (long long)blockIdx.x * BN;

  const TA* Ab = A + (long long)batch * a_bstride;
  const TB* Bb = B + (long long)batch * b_bstride;

  const int sr = tid >> 2;        // staging row 0..63
  const int sc = (tid & 3) * 8;   // staging col 0,8,16,24

  f32x4 acc[4] = {};

  for (int k0 = 0; k0 < K; k0 += BK) {
    stage8(&As[sr][sc], Ab + (m0 + sr) * (long long)lda + k0 + sc);
    stage8(&Bs[sr][sc], Bb + (n0 + sr) * (long long)ldb + k0 + sc);
    __syncthreads();

    const int kq = (lane >> 4) * 8;
    bf16x8 bfrag = *(const bf16x8*)&Bs[wave * 16 + (lane & 15)][kq];
#pragma unroll
    for (int t = 0; t < 4; ++t) {
      bf16x8 afrag = *(const bf16x8*)&As[t * 16 + (lane & 15)][kq];
      acc[t] = __builtin_amdgcn_mfma_f32_16x16x32_bf16(afrag, bfrag, acc[t], 0, 0, 0);
    }
    __syncthreads();
  }

  // Epilogue. D[m][n]: m_rel = (lane>>4)*4 + r, n_rel = lane&15 (per 16-wide col tile)
  const long long col = n0 + wave * 16 + (lane & 15);
#pragma unroll
  for (int t = 0; t < 4; ++t) {
#pragma unroll
    for (int r = 0; r < 4; ++r) {
      const long long row = m0 + t * 16 + (lane >> 4) * 4 + r;
      float v = acc[t][r];
      if (MODE == MODE_QCAT) {
        v = (v + bias[col]) * alpha;
        const long long h = col >> 6, kk = col & 63, n = row >> 9, i = row & 511;
        ((unsigned short*)Cv)[((h * 512 + i) << 12) + (n << 6) + kk] = f2bf(v);
      } else if (MODE == MODE_VT) {
        v = v + bias[col];
        const long long h = col >> 6, kk = col & 63, n = row >> 9, j = row & 511;
        ((unsigned short*)Cv)[(((h << 12) + (n << 6) + kk) << 9) + j] = f2bf(v);
      } else if (MODE == MODE_ATT) {
        ((float*)Cv)[((long long)batch << 18) + (row << 9) + col] = v;
      } else if (MODE == MODE_OUTWS) {
        const long long n = col >> 6, kk = col & 63;
        ((unsigned short*)Cv)[(n * 512 + row) * 768 + (long long)batch * 64 + kk] = f2bf(v);
      } else {  // MODE_OUT_BIAS
        ((float*)Cv)[row * 768 + col] = v + bias[col];
      }
    }
  }
}

// softmax over last dim: att fp32 [12][512][512] -> att_b bf16, one block per row
__global__ __launch_bounds__(256) void softmax_rows(const float* __restrict__ att,
                                                    unsigned short* __restrict__ outb) {
  const long long rowbase = (long long)blockIdx.x << 9;
  const int tid = threadIdx.x;
  float a = att[rowbase + tid];
  float b = att[rowbase + tid + 256];

  float m = fmaxf(a, b);
#pragma unroll
  for (int off = 32; off; off >>= 1) m = fmaxf(m, __shfl_down(m, off));
  __shared__ float redm[4];
  if ((tid & 63) == 0) redm[tid >> 6] = m;
  __syncthreads();
  m = fmaxf(fmaxf(redm[0], redm[1]), fmaxf(redm[2], redm[3]));

  const float e0 = __expf(a - m), e1 = __expf(b - m);
  float s = e0 + e1;
#pragma unroll
  for (int off = 32; off; off >>= 1) s += __shfl_down(s, off);
  __shared__ float reds[4];
  if ((tid & 63) == 0) reds[tid >> 6] = s;
  __syncthreads();
  s = reds[0] + reds[1] + reds[2] + reds[3];

  const float inv = 1.0f / s;
  outb[rowbase + tid] = f2bf(e0 * inv);
  outb[rowbase + tid + 256] = f2bf(e1 * inv);
}

extern "C" void kernel_launch(void* const* d_in, const int* in_sizes, int n_in,
                              void* d_out, int out_size, void* d_ws, size_t ws_size,
                              hipStream_t stream) {
  const float* query = (const float*)d_in[0];
  const float* key   = (const float*)d_in[1];
  const float* value = (const float*)d_in[2];
  const float* Wq = (const float*)d_in[3];
  const float* bq = (const float*)d_in[4];
  const float* Wk = (const float*)d_in[5];
  const float* bk = (const float*)d_in[6];
  const float* Wv = (const float*)d_in[7];
  const float* bv = (const float*)d_in[8];
  const float* Wo = (const float*)d_in[9];
  const float* bo = (const float*)d_in[10];
  float* out = (float*)d_out;

  char* ws = (char*)d_ws;
  unsigned short* q_ws  = (unsigned short*)(ws);               // 50,331,648 B
  unsigned short* k_ws  = (unsigned short*)(ws + 50331648);    // 50,331,648 B
  unsigned short* vt_ws = (unsigned short*)(ws + 100663296);   // 50,331,648 B
  float*          att   = (float*)(ws + 150994944);            // 12,582,912 B
  unsigned short* att_b = k_ws;   // reuse: k_ws dead after s2
  unsigned short* out_ws = q_ws;  // reuse: q_ws dead after s2

  const dim3 blk(256);

  // s1: projections (fp32 sources converted to bf16 during staging)
  gemm_bt<float, float, MODE_QCAT><<<dim3(12, 512, 1), blk, 0, stream>>>(
      query, Wq, bq, q_ws, 32768, 768, 768, 768, 768, 0, 0, 0.015625f);
  gemm_bt<float, float, MODE_QCAT><<<dim3(12, 512, 1), blk, 0, stream>>>(
      key, Wk, bk, k_ws, 32768, 768, 768, 768, 768, 0, 0, 1.0f);
  gemm_bt<float, float, MODE_VT><<<dim3(12, 512, 1), blk, 0, stream>>>(
      value, Wv, bv, vt_ws, 32768, 768, 768, 768, 768, 0, 0, 1.0f);

  // s2: tied scores, per-head [512 x 4096] @ [512 x 4096]^T
  gemm_bt<unsigned short, unsigned short, MODE_ATT><<<dim3(8, 8, 12), blk, 0, stream>>>(
      q_ws, k_ws, nullptr, att, 512, 512, 4096, 4096, 4096,
      2097152LL, 2097152LL, 1.0f);

  // s3: softmax
  softmax_rows<<<6144, 256, 0, stream>>>(att, att_b);

  // s4: per-head att @ V  -> out_ws [(n*512+i)][h*64+k]
  gemm_bt<unsigned short, unsigned short, MODE_OUTWS><<<dim3(64, 8, 12), blk, 0, stream>>>(
      att_b, vt_ws, nullptr, out_ws, 512, 4096, 512, 512, 512,
      262144LL, 2097152LL, 1.0f);

  // s5: output projection -> fp32 d_out
  gemm_bt<unsigned short, float, MODE_OUT_BIAS><<<dim3(12, 512, 1), blk, 0, stream>>>(
      out_ws, Wo, bo, out, 32768, 768, 768, 768, 768, 0, 0, 1.0f);
}

// Round 2
// 727.185 us; speedup vs baseline: 1.3368x; 1.3368x over previous
//
#include <hip/hip_runtime.h>

// ---------------------------------------------------------------------------
// TiedMultiheadAttention  (B=1, N=64, L=512, D=768, H=12, DK=64)
//
// R2: 128x128-tile MFMA GEMM (4 waves, 4x4 frags each), m97-style
//     global_load_lds(16B) staging for bf16 GEMMs, VGPR-convert staging for
//     fp32-source projections, XCD-aware swizzle, split-K x4 on scores.
// ---------------------------------------------------------------------------

typedef __bf16 bf16x8 __attribute__((ext_vector_type(8)));
typedef float f32x4 __attribute__((ext_vector_type(4)));

__device__ __forceinline__ unsigned short f2bf(float f) {
  unsigned u = __float_as_uint(f);
  u += 0x7fffu + ((u >> 16) & 1u);  // RNE
  return (unsigned short)(u >> 16);
}

__device__ __forceinline__ void gll16(const unsigned short* g, unsigned short* l) {
  __builtin_amdgcn_global_load_lds(
      (const __attribute__((address_space(1))) unsigned int*)g,
      (__attribute__((address_space(3))) unsigned int*)l, 16, 0, 0);
}

template <bool C, typename T1, typename T2> struct Cond { using type = T1; };
template <typename T1, typename T2> struct Cond<false, T1, T2> { using type = T2; };

enum { MODE_QCAT = 0, MODE_VT = 1, MODE_ATT = 2, MODE_OUTWS = 3, MODE_OUT_BIAS = 4 };

constexpr int BM = 128, BN = 128, BK = 32;

// C = A @ B^T. A:[M,K] lda, B:[N,K] ldb. Batch via blockIdx.z (opt split-K).
// F32S: A/B are fp32, converted to bf16 in VGPRs during staging (padded LDS).
// else: A/B bf16, staged via global_load_lds (unpadded m97 layout).
// SWZ : XCD-aware block swizzle, requires ntiles_m % 8 == 0, 1-D grid.
template <int MODE, bool F32S, bool SWZ, int KS>
__global__ __launch_bounds__(256, 2) void gemm_bt(
    const void* __restrict__ Av, const void* __restrict__ Bv,
    const float* __restrict__ bias, void* __restrict__ Cv,
    int K, int lda, int ldb, long long a_bs, long long b_bs,
    float alpha, int ntn) {
  using T = typename Cond<F32S, float, unsigned short>::type;
  constexpr int LP = F32S ? 40 : 32;  // row stride in bf16 elems

  __shared__ unsigned short As[BM * LP];
  __shared__ unsigned short Bs[BN * LP];

  const int tid = threadIdx.x;
  const int wave = tid >> 6;
  const int lane = tid & 63;
  const int wm = wave >> 1, wn = wave & 1;

  int tm, tn;
  if constexpr (SWZ) {
    const int bid = blockIdx.x;
    const int xcd = bid & 7;
    const int k = bid >> 3;
    tn = k % ntn;
    tm = (k / ntn) * 8 + xcd;
  } else {
    tn = blockIdx.x;
    tm = blockIdx.y;
  }
  int batch = blockIdx.z, ks = 0;
  if constexpr (KS > 1) { ks = batch % KS; batch /= KS; }

  const long long m0 = (long long)tm * BM;
  const long long n0 = (long long)tn * BN;

  const T* Ab = (const T*)Av + (long long)batch * a_bs + (long long)ks * K;
  const T* Bb = (const T*)Bv + (long long)batch * b_bs + (long long)ks * K;

  f32x4 acc[4][4] = {};

  const int l15 = lane & 15;
  const int kq = (lane >> 4) * 8;

  for (int k0 = 0; k0 < K; k0 += BK) {
    if constexpr (F32S) {
      const int row = tid >> 3;          // 0..31
      const int c4 = (tid & 7) * 4;      // 0,4,..,28
#pragma unroll
      for (int rr = 0; rr < 4; ++rr) {
        const int r = row + rr * 32;
        const float4 av = *(const float4*)((const float*)Ab + (m0 + r) * (long long)lda + k0 + c4);
        const float4 bv = *(const float4*)((const float*)Bb + (n0 + r) * (long long)ldb + k0 + c4);
        ushort4 ap{f2bf(av.x), f2bf(av.y), f2bf(av.z), f2bf(av.w)};
        ushort4 bp{f2bf(bv.x), f2bf(bv.y), f2bf(bv.z), f2bf(bv.w)};
        *(ushort4*)&As[r * LP + c4] = ap;
        *(ushort4*)&Bs[r * LP + c4] = bp;
      }
    } else {
      const int r_in = lane >> 2;        // 0..15
      const int c8 = (lane & 3) * 8;     // 0,8,16,24
#pragma unroll
      for (int t = 0; t < 2; ++t) {
        const int rb = t * 64 + wave * 16;  // wave-uniform row base
        gll16((const unsigned short*)Ab + (m0 + rb + r_in) * (long long)lda + k0 + c8,
              &As[rb * LP]);
        gll16((const unsigned short*)Bb + (n0 + rb + r_in) * (long long)ldb + k0 + c8,
              &Bs[rb * LP]);
      }
    }
    __syncthreads();

    bf16x8 af[4], bfr[4];
#pragma unroll
    for (int t = 0; t < 4; ++t)
      af[t] = *(const bf16x8*)&As[(wm * 64 + t * 16 + l15) * LP + kq];
#pragma unroll
    for (int u = 0; u < 4; ++u)
      bfr[u] = *(const bf16x8*)&Bs[(wn * 64 + u * 16 + l15) * LP + kq];
#pragma unroll
    for (int t = 0; t < 4; ++t)
#pragma unroll
      for (int u = 0; u < 4; ++u)
        acc[t][u] = __builtin_amdgcn_mfma_f32_16x16x32_bf16(af[t], bfr[u], acc[t][u], 0, 0, 0);
    __syncthreads();
  }

  // Epilogue: D[m][n] with m_rel=(lane>>4)*4+r, n_rel=lane&15 per 16x16 tile
#pragma unroll
  for (int t = 0; t < 4; ++t) {
#pragma unroll
    for (int u = 0; u < 4; ++u) {
      const long long col = n0 + wn * 64 + u * 16 + l15;
#pragma unroll
      for (int r = 0; r < 4; ++r) {
        const long long row = m0 + wm * 64 + t * 16 + (lane >> 4) * 4 + r;
        float v = acc[t][u][r];
        if constexpr (MODE == MODE_QCAT) {
          v = (v + bias[col]) * alpha;
          const long long h = col >> 6, kk = col & 63, n = row >> 9, i = row & 511;
          ((unsigned short*)Cv)[((h * 512 + i) << 12) + (n << 6) + kk] = f2bf(v);
        } else if constexpr (MODE == MODE_VT) {
          v = v + bias[col];
          const long long h = col >> 6, kk = col & 63, n = row >> 9, j = row & 511;
          ((unsigned short*)Cv)[(((h << 12) + (n << 6) + kk) << 9) + j] = f2bf(v);
        } else if constexpr (MODE == MODE_ATT) {
          float* p = &((float*)Cv)[((long long)batch << 18) + (row << 9) + col];
          if constexpr (KS > 1) atomicAdd(p, v); else *p = v;
        } else if constexpr (MODE == MODE_OUTWS) {
          const long long n = col >> 6, kk = col & 63;
          ((unsigned short*)Cv)[(n * 512 + row) * 768 + (long long)batch * 64 + kk] = f2bf(v);
        } else {  // MODE_OUT_BIAS
          ((float*)Cv)[row * 768 + col] = v + bias[col];
        }
      }
    }
  }
}

// softmax over last dim: att fp32 [12][512][512] -> bf16
__global__ __launch_bounds__(256) void softmax_rows(const float* __restrict__ att,
                                                    unsigned short* __restrict__ outb) {
  const long long rowbase = (long long)blockIdx.x << 9;
  const int tid = threadIdx.x;
  float a = att[rowbase + tid];
  float b = att[rowbase + tid + 256];

  float m = fmaxf(a, b);
#pragma unroll
  for (int off = 32; off; off >>= 1) m = fmaxf(m, __shfl_down(m, off));
  __shared__ float redm[4];
  if ((tid & 63) == 0) redm[tid >> 6] = m;
  __syncthreads();
  m = fmaxf(fmaxf(redm[0], redm[1]), fmaxf(redm[2], redm[3]));

  const float e0 = __expf(a - m), e1 = __expf(b - m);
  float s = e0 + e1;
#pragma unroll
  for (int off = 32; off; off >>= 1) s += __shfl_down(s, off);
  __shared__ float reds[4];
  if ((tid & 63) == 0) reds[tid >> 6] = s;
  __syncthreads();
  s = reds[0] + reds[1] + reds[2] + reds[3];

  const float inv = 1.0f / s;
  outb[rowbase + tid] = f2bf(e0 * inv);
  outb[rowbase + tid + 256] = f2bf(e1 * inv);
}

// fp32 -> bf16, 8 elems/thread (n must be multiple of 2048)
__global__ __launch_bounds__(256) void cvt_bf16(const float* __restrict__ in,
                                                unsigned short* __restrict__ out) {
  const long long i = ((long long)blockIdx.x * 256 + threadIdx.x) * 8;
  const float4 a = *(const float4*)(in + i);
  const float4 b = *(const float4*)(in + i + 4);
  uint4 p;
  p.x = (unsigned)f2bf(a.x) | ((unsigned)f2bf(a.y) << 16);
  p.y = (unsigned)f2bf(a.z) | ((unsigned)f2bf(a.w) << 16);
  p.z = (unsigned)f2bf(b.x) | ((unsigned)f2bf(b.y) << 16);
  p.w = (unsigned)f2bf(b.z) | ((unsigned)f2bf(b.w) << 16);
  *(uint4*)(out + i) = p;
}

extern "C" void kernel_launch(void* const* d_in, const int* in_sizes, int n_in,
                              void* d_out, int out_size, void* d_ws, size_t ws_size,
                              hipStream_t stream) {
  const float* query = (const float*)d_in[0];
  const float* key   = (const float*)d_in[1];
  const float* value = (const float*)d_in[2];
  const float* Wq = (const float*)d_in[3];
  const float* bq = (const float*)d_in[4];
  const float* Wk = (const float*)d_in[5];
  const float* bk = (const float*)d_in[6];
  const float* Wv = (const float*)d_in[7];
  const float* bv = (const float*)d_in[8];
  const float* Wo = (const float*)d_in[9];
  const float* bo = (const float*)d_in[10];
  float* out = (float*)d_out;

  char* ws = (char*)d_ws;
  unsigned short* q_ws  = (unsigned short*)(ws);               // 50,331,648 B
  unsigned short* k_ws  = (unsigned short*)(ws + 50331648);    // 50,331,648 B
  unsigned short* vt_ws = (unsigned short*)(ws + 100663296);   // 50,331,648 B
  float*          att   = (float*)(ws + 150994944);            // 12,582,912 B
  unsigned short* wo_b  = (unsigned short*)(ws + 163577856);   //  1,179,648 B
  unsigned short* att_b = k_ws;   // k_ws dead after s2
  unsigned short* out_ws = q_ws;  // q_ws dead after s2

  const dim3 blk(256);

  // Wo fp32 -> bf16 (589824 elems = 288 * 2048)
  cvt_bf16<<<288, blk, 0, stream>>>(Wo, wo_b);

  // s1: projections (fp32 sources, fused convert), XCD swizzle (ntm=256, ntn=6)
  gemm_bt<MODE_QCAT, true, true, 1><<<dim3(1536, 1, 1), blk, 0, stream>>>(
      query, Wq, bq, q_ws, 768, 768, 768, 0, 0, 0.015625f, 6);
  gemm_bt<MODE_QCAT, true, true, 1><<<dim3(1536, 1, 1), blk, 0, stream>>>(
      key, Wk, bk, k_ws, 768, 768, 768, 0, 0, 1.0f, 6);
  gemm_bt<MODE_VT, true, true, 1><<<dim3(1536, 1, 1), blk, 0, stream>>>(
      value, Wv, bv, vt_ws, 768, 768, 768, 0, 0, 1.0f, 6);

  // s2: tied scores, per-head [512 x 4096] @ [512 x 4096]^T, split-K x4
  hipMemsetAsync(att, 0, 12582912, stream);
  gemm_bt<MODE_ATT, false, false, 4><<<dim3(4, 4, 48), blk, 0, stream>>>(
      q_ws, k_ws, nullptr, att, 1024, 4096, 4096, 2097152LL, 2097152LL, 1.0f, 4);

  // s3: softmax
  softmax_rows<<<6144, blk, 0, stream>>>(att, att_b);

  // s4: per-head att @ Vt^T -> out_ws [(n*512+i)][h*64+k]
  gemm_bt<MODE_OUTWS, false, false, 1><<<dim3(32, 4, 12), blk, 0, stream>>>(
      att_b, vt_ws, nullptr, out_ws, 512, 512, 512, 262144LL, 2097152LL, 1.0f, 32);

  // s5: output projection -> fp32 d_out, XCD swizzle
  gemm_bt<MODE_OUT_BIAS, false, true, 1><<<dim3(1536, 1, 1), blk, 0, stream>>>(
      out_ws, wo_b, bo, out, 768, 768, 768, 0, 0, 1.0f, 6);
}